// Round 9
// baseline (273.590 us; speedup 1.0000x reference)
//
#include <hip/hip_runtime.h>
#include <hip/hip_bf16.h>

// Net_27358941675610: the 50-step scan collapses to its fixed point:
//   R   = 0.35*sigmoid((6/7)*(psp^T @ W_h^T + b_h))            [4096,2048]
//   out = 0.35*sigmoid(0.75*(R @ W_o^T + b_o) + 0.125*label)   [4096,512]
// Inputs fp32, output fp32. Internal: bf16 MFMA, fp32 acc.
// R9: ONE fused kernel (prep -> barrier -> GEMM1 -> barrier -> GEMM2) +
// 128B memset for the barrier counter. 512 blocks x 256 thr, LB(256,2):
// LDS 32KB (<=5 blk/CU) and VGPR<=256 (8 waves/CU) guarantee 2 blk/CU =>
// all 512 blocks co-resident => manual grid barrier cannot deadlock.

typedef __bf16 bf16_t;
typedef __bf16 bf16x8 __attribute__((ext_vector_type(8)));
typedef __bf16 bf16x4v __attribute__((ext_vector_type(4)));
typedef float f32x4 __attribute__((ext_vector_type(4)));

#define GLD_TO_LDS16(gp, lp)                                            \
  __builtin_amdgcn_global_load_lds(                                     \
      (__attribute__((address_space(1))) void*)(void*)(gp),             \
      (__attribute__((address_space(3))) void*)(lp), 16, 0, 0)

// Cumulative-target grid barrier: each block adds 1; pass k waits for k*512.
// Counter zeroed by hipMemsetAsync every call (replay-safe).
__device__ __forceinline__ void grid_barrier(unsigned* ctr, unsigned target) {
  __syncthreads();
  if (threadIdx.x == 0) {
    __threadfence();  // publish prior global writes (agent scope)
    __hip_atomic_fetch_add(ctr, 1u, __ATOMIC_ACQ_REL, __HIP_MEMORY_SCOPE_AGENT);
    while (__hip_atomic_load(ctr, __ATOMIC_ACQUIRE, __HIP_MEMORY_SCOPE_AGENT) <
           target) {
      __builtin_amdgcn_s_sleep(2);
    }
    __threadfence();  // acquire: invalidate stale L1/L2 before phase reads
  }
  __syncthreads();
}

__global__ __launch_bounds__(256, 2) void fused_all(
    const float* __restrict__ psp,   // [1024, 4096]
    const float* __restrict__ Wh,    // [2048, 1024]
    const float* __restrict__ Wo,    // [512, 2048]
    const float* __restrict__ bh,    // [2048]
    const float* __restrict__ bo,    // [512]
    const float* __restrict__ lbl,   // [4096, 512]
    bf16_t* __restrict__ pspT,       // ws [4096, 1024]
    bf16_t* __restrict__ Whb,        // ws [2048, 1024]
    bf16_t* __restrict__ Wob,        // ws [512, 2048]
    bf16_t* __restrict__ Rm,         // ws [4096, 2048]
    float* __restrict__ out,         // [4096, 512]
    unsigned* __restrict__ ctr) {
  __shared__ __align__(16) char smem[32768];
  const int tid = threadIdx.x;
  const int b = blockIdx.x;
  const int wave = tid >> 6;
  const int lane = tid & 63;

  // ---------------- Phase P: transpose psp + convert weights --------------
  {
    float(*tile)[65] = (float(*)[65])smem;
    const int tx = tid & 63;
    const int ty = tid >> 6;
#pragma unroll
    for (int tt = 0; tt < 2; ++tt) {
      const int t = b * 2 + tt;               // 1024 tiles of 64x64
      const int c0 = (t & 63) * 64;           // batch dim (4096)
      const int r0 = (t >> 6) * 64;           // in dim (1024)
      if (tt) __syncthreads();
#pragma unroll
      for (int i = 0; i < 16; ++i) {
        const int r = ty + i * 4;
        tile[r][tx] = psp[(size_t)(r0 + r) * 4096 + c0 + tx];
      }
      __syncthreads();
#pragma unroll
      for (int i = 0; i < 16; ++i) {
        const int r = ty + i * 4;
        pspT[(size_t)(c0 + r) * 1024 + r0 + tx] = (bf16_t)tile[tx][r];
      }
    }
    // weights: 524288 (Wh) + 262144 (Wo) float4, 1536 per block
    const int base = b * 1536 + tid;
#pragma unroll
    for (int i = 0; i < 6; ++i) {
      const int idx = base + i * 256;
      const float4 v = (idx < 524288) ? ((const float4*)Wh)[idx]
                                      : ((const float4*)Wo)[idx - 524288];
      bf16x4v o;
      o.x = (bf16_t)v.x; o.y = (bf16_t)v.y;
      o.z = (bf16_t)v.z; o.w = (bf16_t)v.w;
      if (idx < 524288) ((bf16x4v*)Whb)[idx] = o;
      else ((bf16x4v*)Wob)[idx - 524288] = o;
    }
  }
  grid_barrier(ctr, 512);

  const int fr = lane & 15;
  const int qh = lane >> 4;
  const int srow8 = lane >> 3;
  const int gsegw = (lane & 7) ^ srow8;
  const int cm0 = (lane >> 4) * 4;

  // ---------------- Phase 1: GEMM1 (R8 body, proven) ----------------------
  // 128x128 tile, 4 waves of 64x64, BK=64. M=4096 N=2048 K=1024.
  {
    bf16_t* sA = (bf16_t*)smem;          // [128*64]
    bf16_t* sB = sA + 128 * 64;          // [128*64]
    const int bm = (b & 31) * 128;
    const int bn = (b >> 5) * 128;
    const int wm = (wave & 1) * 64;
    const int wn = (wave >> 1) * 64;

    f32x4 acc[4][4] = {};
    const bf16_t* Ag = pspT + (size_t)(bm + wave * 32 + srow8) * 1024 + gsegw * 8;
    const bf16_t* Bg = Whb + (size_t)(bn + wave * 32 + srow8) * 1024 + gsegw * 8;
    const int dst = wave * 2048;

    for (int k0 = 0; k0 < 1024; k0 += 64) {
#pragma unroll
      for (int c = 0; c < 4; ++c) {
        GLD_TO_LDS16(Ag + (size_t)(c * 8) * 1024 + k0, sA + dst + c * 512);
        GLD_TO_LDS16(Bg + (size_t)(c * 8) * 1024 + k0, sB + dst + c * 512);
      }
      __syncthreads();
#pragma unroll
      for (int ks = 0; ks < 2; ++ks) {
        const int q = ks * 4 + qh;
        bf16x8 av[4], bv[4];
#pragma unroll
        for (int i = 0; i < 4; ++i) {
          const int rr = wm + i * 16 + fr;
          av[i] = *(const bf16x8*)(sA + rr * 64 + ((q ^ (rr & 7)) * 8));
        }
#pragma unroll
        for (int j = 0; j < 4; ++j) {
          const int rr = wn + j * 16 + fr;
          bv[j] = *(const bf16x8*)(sB + rr * 64 + ((q ^ (rr & 7)) * 8));
        }
#pragma unroll
        for (int i = 0; i < 4; ++i)
#pragma unroll
          for (int j = 0; j < 4; ++j)
            acc[i][j] = __builtin_amdgcn_mfma_f32_16x16x32_bf16(
                av[i], bv[j], acc[i][j], 0, 0, 0);
      }
      __syncthreads();
    }

#pragma unroll
    for (int j = 0; j < 4; ++j) {
      const int gn = bn + wn + j * 16 + fr;
      const float bj = bh[gn];
#pragma unroll
      for (int i = 0; i < 4; ++i) {
#pragma unroll
        for (int r = 0; r < 4; ++r) {
          const int gm = bm + wm + i * 16 + cm0 + r;
          const float z = 0.8571428571428571f * (acc[i][j][r] + bj);
          Rm[(size_t)gm * 2048 + gn] = (bf16_t)(0.35f / (1.0f + __expf(-z)));
        }
      }
    }
  }
  grid_barrier(ctr, 1024);

  // ---------------- Phase 2: GEMM2 (R6/R8 body, proven) -------------------
  // 64x64 tile, 4 waves of 32x32, BK=64. M=4096 N=512 K=2048.
  {
    bf16_t* sA = (bf16_t*)smem;          // [64*64]
    bf16_t* sB = sA + 64 * 64;
    const int bm = (b & 63) * 64;
    const int bn = (b >> 6) * 64;
    const int wm = (wave & 1) * 32;
    const int wn = (wave >> 1) * 32;

    f32x4 acc[2][2] = {};
    const int sseg0 = lane & 7;
    bf16_t* sAw = sA + wave * 1024;
    bf16_t* sBw = sB + wave * 1024;

    for (int k0 = 0; k0 < 2048; k0 += 64) {
#pragma unroll
      for (int c = 0; c < 2; ++c) {
        const int row = (wave * 2 + c) * 8 + srow8;
        const int gseg = sseg0 ^ (row & 7);
        GLD_TO_LDS16(Rm + (size_t)(bm + row) * 2048 + k0 + gseg * 8,
                     sAw + c * 512);
        GLD_TO_LDS16(Wob + (size_t)(bn + row) * 2048 + k0 + gseg * 8,
                     sBw + c * 512);
      }
      __syncthreads();
#pragma unroll
      for (int ks = 0; ks < 2; ++ks) {
        const int q = ks * 4 + qh;
        bf16x8 av[2], bv[2];
#pragma unroll
        for (int i = 0; i < 2; ++i) {
          const int rr = wm + i * 16 + fr;
          av[i] = *(const bf16x8*)(sA + rr * 64 + ((q ^ (rr & 7)) * 8));
        }
#pragma unroll
        for (int j = 0; j < 2; ++j) {
          const int rr = wn + j * 16 + fr;
          bv[j] = *(const bf16x8*)(sB + rr * 64 + ((q ^ (rr & 7)) * 8));
        }
#pragma unroll
        for (int i = 0; i < 2; ++i)
#pragma unroll
          for (int j = 0; j < 2; ++j)
            acc[i][j] = __builtin_amdgcn_mfma_f32_16x16x32_bf16(
                av[i], bv[j], acc[i][j], 0, 0, 0);
      }
      __syncthreads();
    }

#pragma unroll
    for (int j = 0; j < 2; ++j) {
      const int gn = bn + wn + j * 16 + fr;
      const float bj = bo[gn];
#pragma unroll
      for (int i = 0; i < 2; ++i) {
#pragma unroll
        for (int r = 0; r < 4; ++r) {
          const int gm = bm + wm + i * 16 + cm0 + r;
          const float z =
              0.75f * (acc[i][j][r] + bj) + 0.125f * lbl[(size_t)gm * 512 + gn];
          out[(size_t)gm * 512 + gn] = 0.35f / (1.0f + __expf(-z));
        }
      }
    }
  }
}

extern "C" void kernel_launch(void* const* d_in, const int* in_sizes, int n_in,
                              void* d_out, int out_size, void* d_ws, size_t ws_size,
                              hipStream_t stream) {
  constexpr int IN = 1024, HID = 2048, OUT = 512, B = 4096;
  const float* psp = (const float*)d_in[0];
  const float* lbl = (const float*)d_in[1];
  const float* W_h = (const float*)d_in[2];
  const float* b_h = (const float*)d_in[3];
  const float* W_o = (const float*)d_in[4];
  const float* b_o = (const float*)d_in[5];
  float* out = (float*)d_out;

  bf16_t* Whb = (bf16_t*)d_ws;                 // 4 MB
  bf16_t* Wob = Whb + (size_t)HID * IN;        // 2 MB
  bf16_t* pspT = Wob + (size_t)OUT * HID;      // 8 MB
  bf16_t* Rm = pspT + (size_t)B * IN;          // 16 MB
  unsigned* ctr = (unsigned*)(Rm + (size_t)B * HID);  // 128 B @ 30 MB

  hipMemsetAsync(ctr, 0, 128, stream);
  fused_all<<<512, 256, 0, stream>>>(psp, W_h, W_o, b_h, b_o, lbl,
                                     pspT, Whb, Wob, Rm, out, ctr);
}

// Round 10
// 134.493 us; speedup vs baseline: 2.0342x; 2.0342x over previous
//
#include <hip/hip_runtime.h>
#include <hip/hip_bf16.h>

// Net_27358941675610: the 50-step scan collapses to its fixed point:
//   R   = 0.35*sigmoid((6/7)*(psp^T @ W_h^T + b_h))            [4096,2048]
//   out = 0.35*sigmoid(0.75*(R @ W_o^T + b_o) + 0.125*label)   [4096,512]
// Inputs fp32, output fp32. Internal: bf16 MFMA, fp32 acc.
// R10: back to 4-kernel pipeline (R9 fused grid-barrier = L2 wb/inv storm,
// 204us kernel). Occupancy lever: 1024-block grids -> 4 blocks/CU on both
// GEMMs (was 2), sharing the single-buffer staging stall across 4 blocks.

typedef __bf16 bf16_t;
typedef __bf16 bf16x8 __attribute__((ext_vector_type(8)));
typedef __bf16 bf16x4v __attribute__((ext_vector_type(4)));
typedef float f32x4 __attribute__((ext_vector_type(4)));

#define GLD_TO_LDS16(gp, lp)                                            \
  __builtin_amdgcn_global_load_lds(                                     \
      (__attribute__((address_space(1))) void*)(void*)(gp),             \
      (__attribute__((address_space(3))) void*)(lp), 16, 0, 0)

// ---- psp fp32 [R][C] -> pspT bf16 [C][R], 64x64 tiles --------------------
__global__ __launch_bounds__(256) void transpose_cvt(
    const float* __restrict__ in, bf16_t* __restrict__ out, int R, int C) {
  __shared__ float tile[64][65];
  const int tx = threadIdx.x & 63;
  const int ty = threadIdx.x >> 6;
  const int r0 = blockIdx.y * 64;
  const int c0 = blockIdx.x * 64;
#pragma unroll
  for (int i = 0; i < 16; ++i) {
    const int r = ty + i * 4;
    tile[r][tx] = in[(size_t)(r0 + r) * C + c0 + tx];
  }
  __syncthreads();
#pragma unroll
  for (int i = 0; i < 16; ++i) {
    const int r = ty + i * 4;
    out[(size_t)(c0 + r) * R + r0 + tx] = (bf16_t)tile[tx][r];
  }
}

// ---- both weight matrices fp32 -> bf16, one launch -----------------------
__global__ __launch_bounds__(256) void cvt2_f32_bf16(
    const float4* __restrict__ w1, bf16x4v* __restrict__ o1, int n1,
    const float4* __restrict__ w2, bf16x4v* __restrict__ o2, int n2) {
  const int i = blockIdx.x * 256 + threadIdx.x;
  const float4 v = (i < n1) ? w1[i] : w2[i - n1];
  bf16x4v o;
  o.x = (bf16_t)v.x; o.y = (bf16_t)v.y; o.z = (bf16_t)v.z; o.w = (bf16_t)v.w;
  if (i < n1) o1[i] = o;
  else if (i - n1 < n2) o2[i - n1] = o;
}

// ---- GEMM1: R(bf16) = 0.35*sigmoid(6/7*(A @ Bt^T + bias)) ----------------
// 128x64 tile, 4 waves of 64x32, BK=64, grid (32,32)=1024 -> 4 blocks/CU.
// Staging: 8-row chunks; LDS slot (row,s) holds global seg s^(row&7).
__global__ __launch_bounds__(256, 4) void gemm1_nt(
    const bf16_t* __restrict__ A, const bf16_t* __restrict__ Bt,
    const float* __restrict__ bias, bf16_t* __restrict__ C,
    int M, int N, int K) {
  constexpr int BK = 64;
  __shared__ __align__(16) bf16_t sA[128 * BK];  // 16 KB
  __shared__ __align__(16) bf16_t sB[64 * BK];   // 8 KB

  const int tid = threadIdx.x;
  const int wave = tid >> 6;  // 0..3
  const int lane = tid & 63;
  const int bm = blockIdx.x * 128;
  const int bn = blockIdx.y * 64;
  const int wm = (wave & 1) * 64;
  const int wn = (wave >> 1) * 32;

  f32x4 acc[4][2] = {};

  const int srow8 = lane >> 3;               // row within 8-row chunk
  const int gseg = (lane & 7) ^ srow8;       // swizzled global 16B segment
  // wave w stages A rows w*32..w*32+31 (4 chunks), B rows w*16..w*16+15 (2)
  const bf16_t* Ag = A + (size_t)(bm + wave * 32 + srow8) * K + gseg * 8;
  const bf16_t* Bg = Bt + (size_t)(bn + wave * 16 + srow8) * K + gseg * 8;
  const int dstA = wave * 2048;
  const int dstB = wave * 1024;

  const int fr = lane & 15;
  const int qh = lane >> 4;

  for (int k0 = 0; k0 < K; k0 += BK) {
#pragma unroll
    for (int c = 0; c < 4; ++c)
      GLD_TO_LDS16(Ag + (size_t)(c * 8) * K + k0, sA + dstA + c * 512);
#pragma unroll
    for (int c = 0; c < 2; ++c)
      GLD_TO_LDS16(Bg + (size_t)(c * 8) * K + k0, sB + dstB + c * 512);
    __syncthreads();  // drains vmcnt, publishes tiles

#pragma unroll
    for (int ks = 0; ks < 2; ++ks) {
      const int q = ks * 4 + qh;  // 16B k-segment 0..7
      bf16x8 av[4], bv[2];
#pragma unroll
      for (int i = 0; i < 4; ++i) {
        const int rr = wm + i * 16 + fr;
        av[i] = *(const bf16x8*)(sA + rr * BK + ((q ^ (rr & 7)) * 8));
      }
#pragma unroll
      for (int j = 0; j < 2; ++j) {
        const int rr = wn + j * 16 + fr;
        bv[j] = *(const bf16x8*)(sB + rr * BK + ((q ^ (rr & 7)) * 8));
      }
#pragma unroll
      for (int i = 0; i < 4; ++i)
#pragma unroll
        for (int j = 0; j < 2; ++j)
          acc[i][j] = __builtin_amdgcn_mfma_f32_16x16x32_bf16(
              av[i], bv[j], acc[i][j], 0, 0, 0);
    }
    __syncthreads();  // protects buffer reuse
  }

  // epilogue: C/D layout col = lane&15, row = (lane>>4)*4 + r  (m89)
  const int cm0 = (lane >> 4) * 4;
#pragma unroll
  for (int j = 0; j < 2; ++j) {
    const int gn = bn + wn + j * 16 + fr;
    const float bj = bias[gn];
#pragma unroll
    for (int i = 0; i < 4; ++i) {
#pragma unroll
      for (int r = 0; r < 4; ++r) {
        const int gm = bm + wm + i * 16 + cm0 + r;
        const float z = 0.8571428571428571f * (acc[i][j][r] + bj);
        C[(size_t)gm * N + gn] = (bf16_t)(0.35f / (1.0f + __expf(-z)));
      }
    }
  }
}

// ---- GEMM2: out(fp32) = 0.35*sigmoid(0.75*(R @ Wo^T + b_o) + 0.125*lbl) --
// 32x64 tile, 4 waves of 16x32, BK=64, grid (128,8)=1024 -> 4 blocks/CU.
__global__ __launch_bounds__(256, 4) void gemm2_nt(
    const bf16_t* __restrict__ A, const bf16_t* __restrict__ Bt,
    const float* __restrict__ bias, const float* __restrict__ lbl,
    float* __restrict__ out, int M, int N, int K) {
  constexpr int BK = 64;
  __shared__ __align__(16) bf16_t sA[32 * BK];  // 4 KB
  __shared__ __align__(16) bf16_t sB[64 * BK];  // 8 KB

  const int tid = threadIdx.x;
  const int wave = tid >> 6;  // 0..3
  const int lane = tid & 63;
  const int bm = blockIdx.x * 32;
  const int bn = blockIdx.y * 64;
  const int wm = (wave & 1) * 16;
  const int wn = (wave >> 1) * 32;

  f32x4 acc[2] = {};

  const int srow8 = lane >> 3;
  const int gseg = (lane & 7) ^ srow8;
  // wave w stages A chunk w (rows w*8..w*8+7), B chunks 2w,2w+1
  const bf16_t* Ag = A + (size_t)(bm + wave * 8 + srow8) * K + gseg * 8;
  const bf16_t* Bg = Bt + (size_t)(bn + wave * 16 + srow8) * K + gseg * 8;
  const int dstA = wave * 512;
  const int dstB = wave * 1024;

  const int fr = lane & 15;
  const int qh = lane >> 4;

  for (int k0 = 0; k0 < K; k0 += BK) {
    GLD_TO_LDS16(Ag + k0, sA + dstA);
#pragma unroll
    for (int c = 0; c < 2; ++c)
      GLD_TO_LDS16(Bg + (size_t)(c * 8) * K + k0, sB + dstB + c * 512);
    __syncthreads();

#pragma unroll
    for (int ks = 0; ks < 2; ++ks) {
      const int q = ks * 4 + qh;
      const int ra = wm + fr;
      const bf16x8 av =
          *(const bf16x8*)(sA + ra * BK + ((q ^ (ra & 7)) * 8));
      bf16x8 bv[2];
#pragma unroll
      for (int j = 0; j < 2; ++j) {
        const int rr = wn + j * 16 + fr;
        bv[j] = *(const bf16x8*)(sB + rr * BK + ((q ^ (rr & 7)) * 8));
      }
#pragma unroll
      for (int j = 0; j < 2; ++j)
        acc[j] = __builtin_amdgcn_mfma_f32_16x16x32_bf16(av, bv[j], acc[j],
                                                         0, 0, 0);
    }
    __syncthreads();
  }

  const int cm0 = (lane >> 4) * 4;
#pragma unroll
  for (int j = 0; j < 2; ++j) {
    const int gn = bn + wn + j * 16 + fr;
    const float bj = bias[gn];
#pragma unroll
    for (int r = 0; r < 4; ++r) {
      const int gm = bm + wm + cm0 + r;
      const float z =
          0.75f * (acc[j][r] + bj) + 0.125f * lbl[(size_t)gm * N + gn];
      out[(size_t)gm * N + gn] = 0.35f / (1.0f + __expf(-z));
    }
  }
}

extern "C" void kernel_launch(void* const* d_in, const int* in_sizes, int n_in,
                              void* d_out, int out_size, void* d_ws, size_t ws_size,
                              hipStream_t stream) {
  constexpr int IN = 1024, HID = 2048, OUT = 512, B = 4096;
  const float* psp = (const float*)d_in[0];   // [IN, B]
  const float* lbl = (const float*)d_in[1];   // [B, OUT]
  const float* W_h = (const float*)d_in[2];   // [HID, IN]
  const float* b_h = (const float*)d_in[3];   // [HID]
  const float* W_o = (const float*)d_in[4];   // [OUT, HID]
  const float* b_o = (const float*)d_in[5];   // [OUT]
  float* out = (float*)d_out;                 // [B, OUT] fp32

  bf16_t* Whb = (bf16_t*)d_ws;                 // [HID, IN]  4 MB
  bf16_t* Wob = Whb + (size_t)HID * IN;        // [OUT, HID] 2 MB
  bf16_t* pspT = Wob + (size_t)OUT * HID;      // [B, IN]    8 MB
  bf16_t* Rm = pspT + (size_t)B * IN;          // [B, HID]  16 MB

  transpose_cvt<<<dim3(B / 64, IN / 64), 256, 0, stream>>>(psp, pspT, IN, B);
  {
    const int n1 = HID * IN / 4, n2 = OUT * HID / 4;
    cvt2_f32_bf16<<<(n1 + n2 + 255) / 256, 256, 0, stream>>>(
        (const float4*)W_h, (bf16x4v*)Whb, n1,
        (const float4*)W_o, (bf16x4v*)Wob, n2);
  }
  gemm1_nt<<<dim3(B / 128, HID / 64), 256, 0, stream>>>(
      pspT, Whb, b_h, Rm, B, HID, IN);
  gemm2_nt<<<dim3(B / 32, OUT / 64), 256, 0, stream>>>(
      Rm, Wob, b_o, lbl, out, B, OUT, HID);
}